// Round 9
// baseline (80.044 us; speedup 1.0000x reference)
//
#include <hip/hip_runtime.h>
#include <hip/hip_bf16.h>

// MVAS: multi-view routed window attention.
// cv: (1,128,128,256) f32   mv: (1,4,128,128,256) f32   out: (1,128,128,256) f32
// 64 windows (8x8) of 16x16 px; 8 heads x 32ch; route top-4 of 256 (4 views x 64 win).

typedef __attribute__((ext_vector_type(4))) float f32x4;
typedef __attribute__((ext_vector_type(8))) short s16x8;
typedef __attribute__((ext_vector_type(2))) unsigned u32x2;
typedef __attribute__((ext_vector_type(4))) unsigned u32x4;

#define SCALE 0.0625f                      // 256^-0.5
#define LOG2E 1.44269504088896340736f

__device__ inline unsigned cvt_pk_bf16(float lo, float hi) {
  unsigned r;
  asm("v_cvt_pk_bf16_f32 %0, %1, %2" : "=v"(r) : "v"(lo), "v"(hi));
  return r;
}
// Compiler-visible RNE bf16 pack: safe as a direct MFMA operand producer
// (inline-asm defs feeding MFMA reads can miss VALU->MFMA hazard NOPs - r7 NaN).
__device__ inline unsigned pk_bf16_rne(float lo, float hi) {
  unsigned a = __float_as_uint(lo);
  unsigned b = __float_as_uint(hi);
  a += 0x7FFFu + ((a >> 16) & 1u);
  b += 0x7FFFu + ((b >> 16) & 1u);
  return (a >> 16) | (b & 0xFFFF0000u);
}
#if __has_builtin(__builtin_amdgcn_exp2f)
#define EXP2(x) __builtin_amdgcn_exp2f(x)
#else
#define EXP2(x) exp2f(x)
#endif

// ---------------- kernel 1: window means ----------------
__global__ __launch_bounds__(256) void k_means(const float* __restrict__ cv,
                                               const float* __restrict__ mv,
                                               float* __restrict__ qwin,
                                               float* __restrict__ kwin) {
  __shared__ float sm[4][64];
  int wi = blockIdx.x >> 2, cq = blockIdx.x & 3;
  int pq = threadIdx.x >> 6, cl = threadIdx.x & 63;
  int c = cq * 64 + cl;
  const float* base;
  float* dst;
  if (wi < 64) {
    base = cv + ((size_t)((wi >> 3) * 16) * 128 + (wi & 7) * 16) * 256;
    dst = qwin + wi * 256;
  } else {
    int r = wi - 64;
    base = mv + (size_t)(r >> 6) * (128 * 128 * 256)
         + ((size_t)(((r >> 3) & 7) * 16) * 128 + (r & 7) * 16) * 256;
    dst = kwin + r * 256;
  }
  float s = 0.f;
  for (int k = 0; k < 64; ++k) {
    int px = pq * 64 + k;
    s += base[((px >> 4) * 128 + (px & 15)) * 256 + c];
  }
  sm[pq][cl] = s;
  __syncthreads();
  if (pq == 0)
    dst[c] = (sm[0][cl] + sm[1][cl] + sm[2][cl] + sm[3][cl]) * (1.f / 256.f);
}

// ---------------- kernel 2: routing logits + top-4 (parallel argmax) ----------------
__global__ __launch_bounds__(256) void k_route(const float* __restrict__ qwin,
                                               const float* __restrict__ kwin,
                                               int* __restrict__ ridx) {
  __shared__ float qrow[256];
  __shared__ float sv[256];
  __shared__ float wbv[4];
  __shared__ int wbi[4];
  int p = blockIdx.x, t = threadIdx.x;
  qrow[t] = qwin[p * 256 + t] * SCALE;
  __syncthreads();
  const f32x4* kr = reinterpret_cast<const f32x4*>(kwin + t * 256);
  float dot = 0.f;
#pragma unroll 4
  for (int c4 = 0; c4 < 64; ++c4) {
    f32x4 kv = kr[c4];
    dot += qrow[c4 * 4 + 0] * kv[0] + qrow[c4 * 4 + 1] * kv[1]
         + qrow[c4 * 4 + 2] * kv[2] + qrow[c4 * 4 + 3] * kv[3];
  }
  sv[t] = dot;
  __syncthreads();
  for (int k = 0; k < 4; ++k) {
    float v = sv[t];
    int ii = t;
#pragma unroll
    for (int off = 32; off > 0; off >>= 1) {
      float ov = __shfl_down(v, off, 64);
      int oi = __shfl_down(ii, off, 64);
      if (ov > v || (ov == v && oi < ii)) { v = ov; ii = oi; }
    }
    if ((t & 63) == 0) { wbv[t >> 6] = v; wbi[t >> 6] = ii; }
    __syncthreads();
    if (t == 0) {
      float bv = wbv[0]; int bi = wbi[0];
      for (int j = 1; j < 4; ++j)
        if (wbv[j] > bv || (wbv[j] == bv && wbi[j] < bi)) { bv = wbv[j]; bi = wbi[j]; }
      ridx[p * 4 + k] = bi;
      sv[bi] = -3.0e38f;
    }
    __syncthreads();
  }
}

// ---------------- shared attention core (r8-proven) ----------------
// Wave processes NW routed windows for 64 q rows (qt=0..3) of head m, window p.
// In-register P: k->kv map f(g,j) = (j>>2)*16 + 4g + (j&3) shared by V and P.
template <int NW>
__device__ __forceinline__ void attn_core(const float* __restrict__ cv,
                                          const float* __restrict__ mv,
                                          const int* __restrict__ rwin,
                                          short* kv_lds,
                                          int p, int m, int wv, int lane,
                                          f32x4 accO[4][2], float lsum[4]) {
  const int g = lane >> 4, c16 = lane & 15;
  const int py = p >> 3, px = p & 7;
  const int tid = wv * 64 + lane;

  const float qs = SCALE * LOG2E;
  s16x8 qf[4];
#pragma unroll
  for (int qt = 0; qt < 4; ++qt) {
    const float* qp = cv + ((size_t)((py * 16 + wv * 4 + qt) * 128) + px * 16 + c16) * 256
                         + m * 32 + g * 8;
    f32x4 a = *reinterpret_cast<const f32x4*>(qp);
    f32x4 b = *reinterpret_cast<const f32x4*>(qp + 4);
    union { u32x4 u; s16x8 s; } cu;
    cu.u[0] = cvt_pk_bf16(a[0] * qs, a[1] * qs);
    cu.u[1] = cvt_pk_bf16(a[2] * qs, a[3] * qs);
    cu.u[2] = cvt_pk_bf16(b[0] * qs, b[1] * qs);
    cu.u[3] = cvt_pk_bf16(b[2] * qs, b[3] * qs);
    qf[qt] = cu.s;
  }

#pragma unroll
  for (int qt = 0; qt < 4; ++qt) {
    lsum[qt] = 0.f;
    accO[qt][0] = f32x4{0.f, 0.f, 0.f, 0.f};
    accO[qt][1] = f32x4{0.f, 0.f, 0.f, 0.f};
  }
  const f32x4 zf = {0.f, 0.f, 0.f, 0.f};

  for (int w = 0; w < NW; ++w) {
    if (w) __syncthreads();
    {
      int r = rwin[w];
      const float* srcb = mv + (size_t)(r >> 6) * (128 * 128 * 256)
                        + ((size_t)(((r >> 3) & 7) * 16) * 128 + (r & 7) * 16) * 256 + m * 32;
#pragma unroll
      for (int i = 0; i < 8; ++i) {
        int u = i * 256 + tid;
        int pxl = u >> 3, quad = u & 7;
        f32x4 d = *reinterpret_cast<const f32x4*>(
            srcb + ((pxl >> 4) * 128 + (pxl & 15)) * 256 + quad * 4);
        u32x2 pk;
        pk[0] = cvt_pk_bf16(d[0], d[1]);
        pk[1] = cvt_pk_bf16(d[2], d[3]);
        int off = (pxl >> 2) * 128 + (quad >> 2) * 64 + (pxl & 3) * 16 + (quad & 3) * 4;
        *reinterpret_cast<u32x2*>(&kv_lds[off]) = pk;
      }
    }
    __syncthreads();

    for (int s = 0; s < 8; ++s) {
      int kr0 = s * 32 + c16;
      int kr1 = kr0 + 16;
      const s16x8 kf0 = *reinterpret_cast<const s16x8*>(
          &kv_lds[(kr0 >> 2) * 128 + (g >> 1) * 64 + (kr0 & 3) * 16 + (g & 1) * 8]);
      const s16x8 kf1 = *reinterpret_cast<const s16x8*>(
          &kv_lds[(kr1 >> 2) * 128 + (g >> 1) * 64 + (kr1 & 3) * 16 + (g & 1) * 8]);
      s16x8 V0, V1;
#pragma unroll
      for (int j = 0; j < 8; ++j) {
        int a = (s * 8 + (j >> 2) * 4 + g) * 128 + (j & 3) * 16 + c16;
        V0[j] = kv_lds[a];
        V1[j] = kv_lds[a + 64];
      }
#pragma unroll
      for (int qt = 0; qt < 4; ++qt) {
        f32x4 sx = __builtin_amdgcn_mfma_f32_16x16x32_bf16(kf0, qf[qt], zf, 0, 0, 0);
        f32x4 sy = __builtin_amdgcn_mfma_f32_16x16x32_bf16(kf1, qf[qt], zf, 0, 0, 0);
        float x0 = EXP2(sx[0]), x1 = EXP2(sx[1]), x2 = EXP2(sx[2]), x3 = EXP2(sx[3]);
        float y0 = EXP2(sy[0]), y1 = EXP2(sy[1]), y2 = EXP2(sy[2]), y3 = EXP2(sy[3]);
        lsum[qt] += ((x0 + x1) + (x2 + x3)) + ((y0 + y1) + (y2 + y3));
        union { u32x4 u; s16x8 s; } pb;
        pb.u[0] = pk_bf16_rne(x0, x1);
        pb.u[1] = pk_bf16_rne(x2, x3);
        pb.u[2] = pk_bf16_rne(y0, y1);
        pb.u[3] = pk_bf16_rne(y2, y3);
        accO[qt][0] = __builtin_amdgcn_mfma_f32_16x16x32_bf16(V0, pb.s, accO[qt][0], 0, 0, 0);
        accO[qt][1] = __builtin_amdgcn_mfma_f32_16x16x32_bf16(V1, pb.s, accO[qt][1], 0, 0, 0);
      }
    }
  }
}

// ---------------- kernel 3a: split-KV partial attention ----------------
// block = (p, m, half): 1024 blocks x 4 waves -> 4 blocks/CU (16 waves/CU).
// Writes unnormalized O + l (exact: no-max softmax partials sum).
__global__ __launch_bounds__(256, 4) void k_attn_partial(const float* __restrict__ cv,
                                                         const float* __restrict__ mv,
                                                         const int* __restrict__ ridx,
                                                         float* __restrict__ opart,
                                                         float* __restrict__ lpart) {
  __shared__ __align__(16) short kv_lds[256 * 32];   // 16 KB
  const int tid = threadIdx.x;
  const int lane = tid & 63, wv = tid >> 6;
  const int g = lane >> 4, c16 = lane & 15;
  const int bid = blockIdx.x;
  const int half = bid & 1, m = (bid >> 1) & 7, p = bid >> 4;

  int rwin[2];
  rwin[0] = ridx[p * 4 + half * 2 + 0];
  rwin[1] = ridx[p * 4 + half * 2 + 1];

  f32x4 accO[4][2];
  float lsum[4];
  attn_core<2>(cv, mv, rwin, kv_lds, p, m, wv, lane, accO, lsum);

  // write partials: [half][p][m][q 256][ch 32] f32, coalesced across lanes
  float* Ob = opart + ((size_t)(half * 512 + p * 8 + m) * 256) * 32;
  float* lb = lpart + (size_t)(half * 512 + p * 8 + m) * 256;
#pragma unroll
  for (int qt = 0; qt < 4; ++qt) {
    float l = lsum[qt];
    l += __shfl_xor(l, 16, 64);
    l += __shfl_xor(l, 32, 64);
    int q = (wv * 4 + qt) * 16 + c16;
    if (g == 0) lb[q] = l;
#pragma unroll
    for (int mt = 0; mt < 2; ++mt)
      *reinterpret_cast<f32x4*>(&Ob[q * 32 + mt * 16 + g * 4]) = accO[qt][mt];
  }
}

// ---------------- kernel 3b: merge halves + normalize ----------------
__global__ __launch_bounds__(256) void k_merge(const float* __restrict__ opart,
                                               const float* __restrict__ lpart,
                                               float* __restrict__ out) {
  int uidx = blockIdx.x * 256 + threadIdx.x;   // f32x4 unit of out
  int c4 = uidx & 63;
  int X = (uidx >> 6) & 127;
  int Y = uidx >> 13;
  int p = (Y >> 4) * 8 + (X >> 4);
  int q = (Y & 15) * 16 + (X & 15);
  int m = c4 >> 3, ch4 = c4 & 7;
  size_t pidx = (size_t)(p * 8 + m) * 256 + q;
  const size_t HSTRIDE = (size_t)512 * 256;
  f32x4 o0 = *reinterpret_cast<const f32x4*>(&opart[pidx * 32 + ch4 * 4]);
  f32x4 o1 = *reinterpret_cast<const f32x4*>(&opart[(pidx + HSTRIDE) * 32 + ch4 * 4]);
  float rl = 1.f / (lpart[pidx] + lpart[pidx + HSTRIDE]);
  f32x4 o;
  o[0] = (o0[0] + o1[0]) * rl; o[1] = (o0[1] + o1[1]) * rl;
  o[2] = (o0[2] + o1[2]) * rl; o[3] = (o0[3] + o1[3]) * rl;
  *reinterpret_cast<f32x4*>(&out[(size_t)uidx * 4]) = o;
}

// ---------------- kernel 3 fallback: fused (r8-proven, used if ws too small) --------
__global__ __launch_bounds__(256, 2) void k_attn_fused(const float* __restrict__ cv,
                                                       const float* __restrict__ mv,
                                                       const int* __restrict__ ridx,
                                                       float* __restrict__ out) {
  __shared__ __align__(16) short kv_lds[256 * 32];
  const int tid = threadIdx.x;
  const int lane = tid & 63, wv = tid >> 6;
  const int g = lane >> 4, c16 = lane & 15;
  const int p = blockIdx.x >> 3, m = blockIdx.x & 7;
  const int py = p >> 3, px = p & 7;

  int rwin[4];
#pragma unroll
  for (int w = 0; w < 4; ++w) rwin[w] = ridx[p * 4 + w];

  f32x4 accO[4][2];
  float lsum[4];
  attn_core<4>(cv, mv, rwin, kv_lds, p, m, wv, lane, accO, lsum);

#pragma unroll
  for (int qt = 0; qt < 4; ++qt) {
    float l = lsum[qt];
    l += __shfl_xor(l, 16, 64);
    l += __shfl_xor(l, 32, 64);
    float rl = 1.f / l;
#pragma unroll
    for (int mt = 0; mt < 2; ++mt) {
      f32x4 o = accO[qt][mt];
      o[0] *= rl; o[1] *= rl; o[2] *= rl; o[3] *= rl;
      float* op = out + ((size_t)((py * 16 + wv * 4 + qt) * 128) + px * 16 + c16) * 256
                      + m * 32 + mt * 16 + g * 4;
      *reinterpret_cast<f32x4*>(op) = o;
    }
  }
}

extern "C" void kernel_launch(void* const* d_in, const int* in_sizes, int n_in,
                              void* d_out, int out_size, void* d_ws, size_t ws_size,
                              hipStream_t stream) {
  const float* cv = (const float*)d_in[0];
  const float* mv = (const float*)d_in[1];
  float* out = (float*)d_out;

  // ws layout (bytes): qwin @0 (64K), kwin @64K (256K), ridx @320K (1K),
  // lpart @512K (1M), opart @2M (32M). Need 2M + 32M.
  float* qwin = (float*)d_ws;
  float* kwin = qwin + 16384;
  int* ridx = (int*)(kwin + 65536);
  float* lpart = (float*)((char*)d_ws + (512u << 10));
  float* opart = (float*)((char*)d_ws + (2u << 20));
  const size_t WS_NEED = (2ull << 20) + 2ull * 512 * 256 * 32 * 4;

  k_means<<<1280, 256, 0, stream>>>(cv, mv, qwin, kwin);
  k_route<<<64, 256, 0, stream>>>(qwin, kwin, ridx);
  if (ws_size >= WS_NEED) {
    k_attn_partial<<<1024, 256, 0, stream>>>(cv, mv, ridx, opart, lpart);
    k_merge<<<4096, 256, 0, stream>>>(opart, lpart, out);
  } else {
    k_attn_fused<<<512, 256, 0, stream>>>(cv, mv, ridx, out);
  }
}